// Round 1
// baseline (179.149 us; speedup 1.0000x reference)
//
#include <hip/hip_runtime.h>
#include <hip/hip_bf16.h>

#define F 1024
#define B_ROWS 16384
#define LDSROW 40  // 32 bf16 data + 8 pad (16B) -> 80B rows: only 2-way bank conflicts (free)

typedef short v8s __attribute__((ext_vector_type(8)));
typedef float v4f __attribute__((ext_vector_type(4)));
typedef unsigned short ushort_t;

__device__ __forceinline__ unsigned short f2bf(float f) {
    unsigned int u = __builtin_bit_cast(unsigned int, f);
    u = (u + 0x7FFFu + ((u >> 16) & 1u)) >> 16;  // RNE
    return (unsigned short)u;
}

// Build A = 0.5*(W + W^T) in bf16, zero diagonal. w is packed triu (i<j, row-major).
__global__ void build_A(const float* __restrict__ w, ushort_t* __restrict__ A) {
    int tid = blockIdx.x * blockDim.x + threadIdx.x;  // 0 .. F*F-1
    int i = tid >> 10, j = tid & (F - 1);
    if (i > j) return;
    if (i == j) { A[tid] = 0; return; }
    int k = i * (F - 1) - (i * (i - 1)) / 2 + (j - i - 1);
    unsigned short v = f2bf(0.5f * w[k]);
    A[i * F + j] = v;
    A[j * F + i] = v;
}

// fp32 X -> bf16 (vectorized 4-wide)
__global__ void convert_x(const float* __restrict__ Xf, ushort_t* __restrict__ Xb) {
    int tid = blockIdx.x * blockDim.x + threadIdx.x;
    size_t idx = (size_t)tid * 4;
    float4 v = *(const float4*)(Xf + idx);
    ushort4 o;
    o.x = f2bf(v.x); o.y = f2bf(v.y); o.z = f2bf(v.z); o.w = f2bf(v.w);
    *(ushort4*)(Xb + idx) = o;
}

// Y = Xb @ A  (M=16384, N=1024, K=1024), fused epilogue:
// rowacc[b] += sum over this block's N columns of Xf[b][j] * Y[b][j]
__global__ __launch_bounds__(256) void gemm_kernel(
        const ushort_t* __restrict__ Xb,   // [B_ROWS][F] bf16
        const ushort_t* __restrict__ A,    // [F][F] bf16 symmetric
        const float*   __restrict__ Xf,    // [B_ROWS][F] fp32 (for epilogue)
        float*         __restrict__ rowacc) {
    __shared__ ushort_t As[128 * LDSROW];
    __shared__ ushort_t Bs[128 * LDSROW];

    const int tid   = threadIdx.x;
    const int lane  = tid & 63;
    const int wave  = tid >> 6;
    const int waveM = wave >> 1;     // 0..1
    const int waveN = wave & 1;      // 0..1
    const int quad  = lane >> 4;     // 0..3
    const int l16   = lane & 15;

    const int blockM = blockIdx.y * 128;
    const int blockN = blockIdx.x * 128;

    // staging: thread t loads 16B chunk (row r0, chunk q0) and (row r0+64, chunk q0)
    const int r0 = tid >> 2, q0 = tid & 3;

    v4f acc[4][4];
#pragma unroll
    for (int i = 0; i < 4; i++)
#pragma unroll
        for (int j = 0; j < 4; j++) acc[i][j] = (v4f)(0.0f);

    for (int k0 = 0; k0 < F; k0 += 32) {
        // global loads first (overlap with prior compute before barrier)
        uint4 a0 = *((const uint4*)(Xb + (size_t)(blockM + r0) * F + k0) + q0);
        uint4 a1 = *((const uint4*)(Xb + (size_t)(blockM + 64 + r0) * F + k0) + q0);
        // A is symmetric: stage B-tile as rows [n][k] directly from A rows.
        uint4 b0 = *((const uint4*)(A + (size_t)(blockN + r0) * F + k0) + q0);
        uint4 b1 = *((const uint4*)(A + (size_t)(blockN + 64 + r0) * F + k0) + q0);
        __syncthreads();
        *(uint4*)(As + r0 * LDSROW + q0 * 8)        = a0;
        *(uint4*)(As + (64 + r0) * LDSROW + q0 * 8) = a1;
        *(uint4*)(Bs + r0 * LDSROW + q0 * 8)        = b0;
        *(uint4*)(Bs + (64 + r0) * LDSROW + q0 * 8) = b1;
        __syncthreads();

        v8s af[4], bfr[4];
#pragma unroll
        for (int mi = 0; mi < 4; mi++)
            af[mi] = *(const v8s*)(As + (waveM * 64 + mi * 16 + l16) * LDSROW + quad * 8);
#pragma unroll
        for (int ni = 0; ni < 4; ni++)
            bfr[ni] = *(const v8s*)(Bs + (waveN * 64 + ni * 16 + l16) * LDSROW + quad * 8);
#pragma unroll
        for (int mi = 0; mi < 4; mi++)
#pragma unroll
            for (int ni = 0; ni < 4; ni++)
                acc[mi][ni] = __builtin_amdgcn_mfma_f32_16x16x32_bf16(
                    af[mi], bfr[ni], acc[mi][ni], 0, 0, 0);
    }

    // Epilogue: C/D mapping (verified m89/m91): col = lane&15, row = quad*4 + reg
#pragma unroll
    for (int mi = 0; mi < 4; mi++) {
#pragma unroll
        for (int r = 0; r < 4; r++) {
            const int b = blockM + waveM * 64 + mi * 16 + quad * 4 + r;
            float p = 0.0f;
#pragma unroll
            for (int ni = 0; ni < 4; ni++) {
                const int j = blockN + waveN * 64 + ni * 16 + l16;
                p += acc[mi][ni][r] * Xf[(size_t)b * F + j];
            }
            // reduce over the quad's 16 lanes (bits 0..3 of lane)
            p += __shfl_xor(p, 1);
            p += __shfl_xor(p, 2);
            p += __shfl_xor(p, 4);
            p += __shfl_xor(p, 8);
            if (l16 == 0) atomicAdd(&rowacc[b], p);
        }
    }
}

__global__ void sigmoid_kernel(const float* __restrict__ acc, float* __restrict__ out) {
    int b = blockIdx.x * blockDim.x + threadIdx.x;
    out[b] = 1.0f / (1.0f + __expf(-acc[b]));
}

// Correctness fallback if workspace is too small: direct per-row computation.
__global__ void fallback_kernel(const float* __restrict__ x, const float* __restrict__ w,
                                float* __restrict__ out) {
    __shared__ float xs[F];
    __shared__ float partial[4];
    const int b = blockIdx.x;
    for (int i = threadIdx.x; i < F; i += 256) xs[i] = x[(size_t)b * F + i];
    __syncthreads();
    float s = 0.0f;
    for (int i = threadIdx.x; i < F - 1; i += 256) {
        const float xi = xs[i];
        const int kbase = i * (F - 1) - (i * (i - 1)) / 2 - i - 1;
        for (int j = i + 1; j < F; j++) s += w[kbase + j] * xi * xs[j];
    }
    for (int off = 32; off; off >>= 1) s += __shfl_down(s, off);
    if ((threadIdx.x & 63) == 0) partial[threadIdx.x >> 6] = s;
    __syncthreads();
    if (threadIdx.x == 0) {
        float t = partial[0] + partial[1] + partial[2] + partial[3];
        out[b] = 1.0f / (1.0f + __expf(-t));
    }
}

extern "C" void kernel_launch(void* const* d_in, const int* in_sizes, int n_in,
                              void* d_out, int out_size, void* d_ws, size_t ws_size,
                              hipStream_t stream) {
    const float* x = (const float*)d_in[0];
    const float* w = (const float*)d_in[1];
    float* out = (float*)d_out;

    const size_t acc_bytes = 65536;                       // 16384 fp32 (rounded)
    const size_t A_bytes   = (size_t)F * F * 2;           // 2 MiB bf16
    const size_t Xb_bytes  = (size_t)B_ROWS * F * 2;      // 32 MiB bf16
    const size_t needed = acc_bytes + A_bytes + Xb_bytes;

    if (ws_size < needed) {
        fallback_kernel<<<B_ROWS, 256, 0, stream>>>(x, w, out);
        return;
    }

    float*    acc = (float*)d_ws;
    ushort_t* A   = (ushort_t*)((char*)d_ws + acc_bytes);
    ushort_t* Xb  = (ushort_t*)((char*)d_ws + acc_bytes + A_bytes);

    hipMemsetAsync(acc, 0, B_ROWS * sizeof(float), stream);
    build_A<<<(F * F) / 256, 256, 0, stream>>>(w, A);
    convert_x<<<(B_ROWS * F / 4) / 256, 256, 0, stream>>>(x, Xb);
    dim3 grid(F / 128, B_ROWS / 128);
    gemm_kernel<<<grid, 256, 0, stream>>>(Xb, A, x, acc);
    sigmoid_kernel<<<B_ROWS / 256, 256, 0, stream>>>(acc, out);
}

// Round 2
// 173.179 us; speedup vs baseline: 1.0345x; 1.0345x over previous
//
#include <hip/hip_runtime.h>
#include <hip/hip_bf16.h>

#define F 1024
#define B_ROWS 16384

typedef short v8s __attribute__((ext_vector_type(8)));
typedef float v4f __attribute__((ext_vector_type(4)));
typedef unsigned short ushort_t;

__device__ __forceinline__ unsigned short f2bf(float f) {
    unsigned int u = __builtin_bit_cast(unsigned int, f);
    u = (u + 0x7FFFu + ((u >> 16) & 1u)) >> 16;  // RNE
    return (unsigned short)u;
}

// async global->LDS, 16B per lane. LDS dest = wave-uniform base + lane*16.
__device__ __forceinline__ void gload_lds16(const ushort_t* g, ushort_t* l) {
    __builtin_amdgcn_global_load_lds(
        (const __attribute__((address_space(1))) unsigned int*)g,
        (__attribute__((address_space(3))) unsigned int*)l,
        16, 0, 0);
}

// Build A = 0.5*(W + W^T) in bf16, zero diag. All stores coalesced; the
// transposed-half w reads are uncoalesced but w (2MB) is L2-resident.
__global__ void build_A(const float* __restrict__ w, ushort_t* __restrict__ A) {
    int tid = blockIdx.x * blockDim.x + threadIdx.x;  // 0 .. F*F-1
    int i = tid >> 10, j = tid & (F - 1);
    float v = 0.0f;
    if (i != j) {
        int a = min(i, j), b = max(i, j);
        int k = a * (F - 1) - (a * (a - 1)) / 2 + (b - a - 1);
        v = 0.5f * w[k];
    }
    A[tid] = f2bf(v);
}

// fp32 X -> bf16 (vectorized 4-wide)
__global__ void convert_x(const float* __restrict__ Xf, ushort_t* __restrict__ Xb) {
    int tid = blockIdx.x * blockDim.x + threadIdx.x;
    size_t idx = (size_t)tid * 4;
    float4 v = *(const float4*)(Xf + idx);
    ushort4 o;
    o.x = f2bf(v.x); o.y = f2bf(v.y); o.z = f2bf(v.z); o.w = f2bf(v.w);
    *(ushort4*)(Xb + idx) = o;
}

// Y = Xb @ A  (M=16384, N=1024, K=1024), fused epilogue:
// rowacc[b] += sum_j Xf[b][j] * Y[b][j] over this block's N columns.
// Staging via global_load_lds w=16; LDS rows are 32 bf16 = 64B, unpadded
// (required by the DMA's lane-ordered dest). Bank conflicts broken by an
// XOR swizzle applied on the *global source* side: LDS chunk position c of
// row r holds global chunk c ^ ((r>>1)&3)  -> ds_read_b128 sees 2-way only.
__global__ __launch_bounds__(256) void gemm_kernel(
        const ushort_t* __restrict__ Xb,   // [B_ROWS][F] bf16
        const ushort_t* __restrict__ A,    // [F][F] bf16 symmetric
        const float*   __restrict__ Xf,    // [B_ROWS][F] fp32 (epilogue)
        float*         __restrict__ rowacc) {
    __shared__ ushort_t As[128 * 32];  // 8 KB
    __shared__ ushort_t Bs[128 * 32];  // 8 KB

    const int tid   = threadIdx.x;
    const int lane  = tid & 63;
    const int wave  = tid >> 6;
    const int waveM = wave >> 1;     // 0..1
    const int waveN = wave & 1;      // 0..1
    const int quad  = lane >> 4;     // 0..3
    const int l16   = lane & 15;

    const int blockM = blockIdx.y * 128;
    const int blockN = blockIdx.x * 128;

    // ---- staging addresses (per-lane global, wave-uniform LDS base) ----
    // wave w covers tile rows [w*32, w*32+32) in two 16-row calls.
    // lane i -> local row i>>2, dest chunk i&3; source chunk xor-swizzled.
    const int lrow = lane >> 2;                       // 0..15
    const int csrc = (lane & 3) ^ ((lane >> 3) & 3);  // swizzled source chunk
    const int rowA0 = wave * 32 + lrow;               // call 0 rows
    const int rowA1 = wave * 32 + 16 + lrow;          // call 1 rows

    const ushort_t* gA0 = Xb + (size_t)(blockM + rowA0) * F + csrc * 8;
    const ushort_t* gA1 = Xb + (size_t)(blockM + rowA1) * F + csrc * 8;
    const ushort_t* gB0 = A + (size_t)(blockN + rowA0) * F + csrc * 8;
    const ushort_t* gB1 = A + (size_t)(blockN + rowA1) * F + csrc * 8;
    ushort_t* lA0 = As + (wave * 32) * 32;       // +lane*16B implicit
    ushort_t* lA1 = As + (wave * 32 + 16) * 32;
    ushort_t* lB0 = Bs + (wave * 32) * 32;
    ushort_t* lB1 = Bs + (wave * 32 + 16) * 32;

    // ---- fragment read addresses ----
    // row R = base16 + l16; (R>>1)&3 == (l16>>1)&3 since base16 % 16 == 0.
    const int swz = quad ^ ((l16 >> 1) & 3);

    v4f acc[4][4];
#pragma unroll
    for (int i = 0; i < 4; i++)
#pragma unroll
        for (int j = 0; j < 4; j++) acc[i][j] = (v4f)(0.0f);

    for (int k0 = 0; k0 < F; k0 += 32) {
        __syncthreads();  // previous tile's reads complete before overwrite
        gload_lds16(gA0, lA0);
        gload_lds16(gA1, lA1);
        gload_lds16(gB0, lB0);
        gload_lds16(gB1, lB1);
        gA0 += 32; gA1 += 32; gB0 += 32; gB1 += 32;
        __syncthreads();  // drains vmcnt(0): staged data visible

        v8s af[4], bfr[4];
#pragma unroll
        for (int mi = 0; mi < 4; mi++)
            af[mi] = *(const v8s*)(As + (waveM * 64 + mi * 16 + l16) * 32 + swz * 8);
#pragma unroll
        for (int ni = 0; ni < 4; ni++)
            bfr[ni] = *(const v8s*)(Bs + (waveN * 64 + ni * 16 + l16) * 32 + swz * 8);
#pragma unroll
        for (int mi = 0; mi < 4; mi++)
#pragma unroll
            for (int ni = 0; ni < 4; ni++)
                acc[mi][ni] = __builtin_amdgcn_mfma_f32_16x16x32_bf16(
                    af[mi], bfr[ni], acc[mi][ni], 0, 0, 0);
    }

    // Epilogue: C/D mapping (verified m89/m91): col = lane&15, row = quad*4 + reg
#pragma unroll
    for (int mi = 0; mi < 4; mi++) {
#pragma unroll
        for (int r = 0; r < 4; r++) {
            const int b = blockM + waveM * 64 + mi * 16 + quad * 4 + r;
            float p = 0.0f;
#pragma unroll
            for (int ni = 0; ni < 4; ni++) {
                const int j = blockN + waveN * 64 + ni * 16 + l16;
                p += acc[mi][ni][r] * Xf[(size_t)b * F + j];
            }
            p += __shfl_xor(p, 1);
            p += __shfl_xor(p, 2);
            p += __shfl_xor(p, 4);
            p += __shfl_xor(p, 8);
            if (l16 == 0) atomicAdd(&rowacc[b], p);
        }
    }
}

__global__ void sigmoid_kernel(const float* __restrict__ acc, float* __restrict__ out) {
    int b = blockIdx.x * blockDim.x + threadIdx.x;
    out[b] = 1.0f / (1.0f + __expf(-acc[b]));
}

// Correctness fallback if workspace is too small: direct per-row computation.
__global__ void fallback_kernel(const float* __restrict__ x, const float* __restrict__ w,
                                float* __restrict__ out) {
    __shared__ float xs[F];
    __shared__ float partial[4];
    const int b = blockIdx.x;
    for (int i = threadIdx.x; i < F; i += 256) xs[i] = x[(size_t)b * F + i];
    __syncthreads();
    float s = 0.0f;
    for (int i = threadIdx.x; i < F - 1; i += 256) {
        const float xi = xs[i];
        const int kbase = i * (F - 1) - (i * (i - 1)) / 2 - i - 1;
        for (int j = i + 1; j < F; j++) s += w[kbase + j] * xi * xs[j];
    }
    for (int off = 32; off; off >>= 1) s += __shfl_down(s, off);
    if ((threadIdx.x & 63) == 0) partial[threadIdx.x >> 6] = s;
    __syncthreads();
    if (threadIdx.x == 0) {
        float t = partial[0] + partial[1] + partial[2] + partial[3];
        out[b] = 1.0f / (1.0f + __expf(-t));
    }
}

extern "C" void kernel_launch(void* const* d_in, const int* in_sizes, int n_in,
                              void* d_out, int out_size, void* d_ws, size_t ws_size,
                              hipStream_t stream) {
    const float* x = (const float*)d_in[0];
    const float* w = (const float*)d_in[1];
    float* out = (float*)d_out;

    const size_t acc_bytes = 65536;                       // 16384 fp32 (rounded)
    const size_t A_bytes   = (size_t)F * F * 2;           // 2 MiB bf16
    const size_t Xb_bytes  = (size_t)B_ROWS * F * 2;      // 32 MiB bf16
    const size_t needed = acc_bytes + A_bytes + Xb_bytes;

    if (ws_size < needed) {
        fallback_kernel<<<B_ROWS, 256, 0, stream>>>(x, w, out);
        return;
    }

    float*    acc = (float*)d_ws;
    ushort_t* A   = (ushort_t*)((char*)d_ws + acc_bytes);
    ushort_t* Xb  = (ushort_t*)((char*)d_ws + acc_bytes + A_bytes);

    hipMemsetAsync(acc, 0, B_ROWS * sizeof(float), stream);
    build_A<<<(F * F) / 256, 256, 0, stream>>>(w, A);
    convert_x<<<(B_ROWS * F / 4) / 256, 256, 0, stream>>>(x, Xb);
    dim3 grid(F / 128, B_ROWS / 128);
    gemm_kernel<<<grid, 256, 0, stream>>>(Xb, A, x, acc);
    sigmoid_kernel<<<B_ROWS / 256, 256, 0, stream>>>(acc, out);
}

// Round 3
// 169.002 us; speedup vs baseline: 1.0600x; 1.0247x over previous
//
#include <hip/hip_runtime.h>
#include <hip/hip_bf16.h>

#define F 1024
#define B_ROWS 16384
#define SPLITK 2
#define KSEG (F / SPLITK)  // 512

typedef short v8s __attribute__((ext_vector_type(8)));
typedef float v4f __attribute__((ext_vector_type(4)));
typedef unsigned short v8u __attribute__((ext_vector_type(8)));
typedef unsigned short ushort_t;

__device__ __forceinline__ unsigned short f2bf(float f) {
    unsigned int u = __builtin_bit_cast(unsigned int, f);
    u = (u + 0x7FFFu + ((u >> 16) & 1u)) >> 16;  // RNE
    return (unsigned short)u;
}

// async global->LDS, 16B per lane. LDS dest = wave-uniform base + lane*16.
__device__ __forceinline__ void gload_lds16(const ushort_t* g, ushort_t* l) {
    __builtin_amdgcn_global_load_lds(
        (const __attribute__((address_space(1))) unsigned int*)g,
        (__attribute__((address_space(3))) unsigned int*)l,
        16, 0, 0);
}

// Fused prep: [0,64) zero rowacc; [64,4160) build A = 0.5*(W+W^T) bf16;
// [4160,12352) convert X fp32->bf16, 8 elements/thread.
__global__ __launch_bounds__(256) void prep_kernel(
        const float* __restrict__ w, const float* __restrict__ x,
        ushort_t* __restrict__ A, ushort_t* __restrict__ Xb,
        float* __restrict__ acc) {
    const int bid = blockIdx.x;
    if (bid < 64) {
        acc[bid * 256 + threadIdx.x] = 0.0f;
    } else if (bid < 64 + 4096) {
        int tid = (bid - 64) * 256 + threadIdx.x;  // 0 .. F*F-1
        int i = tid >> 10, j = tid & (F - 1);
        float v = 0.0f;
        if (i != j) {
            int a = min(i, j), b = max(i, j);
            int k = a * (F - 1) - (a * (a - 1)) / 2 + (b - a - 1);
            v = 0.5f * w[k];  // uncoalesced half is L2-resident (w = 2MB)
        }
        A[tid] = f2bf(v);
    } else {
        int tid = (bid - 4160) * 256 + threadIdx.x;  // 0 .. B_ROWS*F/8-1
        size_t idx = (size_t)tid * 8;
        float4 v0 = *(const float4*)(x + idx);
        float4 v1 = *(const float4*)(x + idx + 4);
        v8u o;
        o[0] = f2bf(v0.x); o[1] = f2bf(v0.y); o[2] = f2bf(v0.z); o[3] = f2bf(v0.w);
        o[4] = f2bf(v1.x); o[5] = f2bf(v1.y); o[6] = f2bf(v1.z); o[7] = f2bf(v1.w);
        *(v8u*)(Xb + idx) = o;
    }
}

// Y = Xb @ A (M=16384, N=1024, K=1024), split-K over blockIdx.z, fused
// epilogue: rowacc[b] += sum_j Xf[b][j] * Ypart[b][j] via atomicAdd.
// Staging: global_load_lds w=16, unpadded 64B LDS rows, XOR source-swizzle
// (LDS chunk c of row r holds global chunk c ^ ((r>>1)&3)) -> 2-way
// conflicts only (free, m136). Verified 0 SQ_LDS_BANK_CONFLICT in round 2.
__global__ __launch_bounds__(256) void gemm_kernel(
        const ushort_t* __restrict__ Xb,   // [B_ROWS][F] bf16
        const ushort_t* __restrict__ A,    // [F][F] bf16 symmetric
        const float*   __restrict__ Xf,    // [B_ROWS][F] fp32 (epilogue)
        float*         __restrict__ rowacc) {
    __shared__ ushort_t As[128 * 32];  // 8 KB
    __shared__ ushort_t Bs[128 * 32];  // 8 KB

    const int tid   = threadIdx.x;
    const int lane  = tid & 63;
    const int wave  = tid >> 6;
    const int waveM = wave >> 1;     // 0..1
    const int waveN = wave & 1;      // 0..1
    const int quad  = lane >> 4;     // 0..3
    const int l16   = lane & 15;

    const int blockM = blockIdx.y * 128;
    const int blockN = blockIdx.x * 128;
    const int kBase  = blockIdx.z * KSEG;

    // ---- staging addresses ----
    const int lrow = lane >> 2;                       // 0..15
    const int csrc = (lane & 3) ^ ((lane >> 3) & 3);  // swizzled source chunk
    const int rowA0 = wave * 32 + lrow;
    const int rowA1 = wave * 32 + 16 + lrow;

    const ushort_t* gA0 = Xb + (size_t)(blockM + rowA0) * F + kBase + csrc * 8;
    const ushort_t* gA1 = Xb + (size_t)(blockM + rowA1) * F + kBase + csrc * 8;
    const ushort_t* gB0 = A + (size_t)(blockN + rowA0) * F + kBase + csrc * 8;
    const ushort_t* gB1 = A + (size_t)(blockN + rowA1) * F + kBase + csrc * 8;
    ushort_t* lA0 = As + (wave * 32) * 32;       // +lane*16B implicit
    ushort_t* lA1 = As + (wave * 32 + 16) * 32;
    ushort_t* lB0 = Bs + (wave * 32) * 32;
    ushort_t* lB1 = Bs + (wave * 32 + 16) * 32;

    // fragment-read swizzle: row R = base16 + l16, (R>>1)&3 == (l16>>1)&3
    const int swz = quad ^ ((l16 >> 1) & 3);

    v4f acc[4][4];
#pragma unroll
    for (int i = 0; i < 4; i++)
#pragma unroll
        for (int j = 0; j < 4; j++) acc[i][j] = (v4f)(0.0f);

    for (int k0 = 0; k0 < KSEG; k0 += 32) {
        __syncthreads();  // previous tile's reads complete before overwrite
        gload_lds16(gA0, lA0);
        gload_lds16(gA1, lA1);
        gload_lds16(gB0, lB0);
        gload_lds16(gB1, lB1);
        gA0 += 32; gA1 += 32; gB0 += 32; gB1 += 32;
        __syncthreads();  // drains vmcnt(0): staged data visible

        v8s af[4], bfr[4];
#pragma unroll
        for (int mi = 0; mi < 4; mi++)
            af[mi] = *(const v8s*)(As + (waveM * 64 + mi * 16 + l16) * 32 + swz * 8);
#pragma unroll
        for (int ni = 0; ni < 4; ni++)
            bfr[ni] = *(const v8s*)(Bs + (waveN * 64 + ni * 16 + l16) * 32 + swz * 8);
#pragma unroll
        for (int mi = 0; mi < 4; mi++)
#pragma unroll
            for (int ni = 0; ni < 4; ni++)
                acc[mi][ni] = __builtin_amdgcn_mfma_f32_16x16x32_bf16(
                    af[mi], bfr[ni], acc[mi][ni], 0, 0, 0);
    }

    // Epilogue: C/D mapping (verified m89/m91): col = lane&15, row = quad*4 + reg
#pragma unroll
    for (int mi = 0; mi < 4; mi++) {
#pragma unroll
        for (int r = 0; r < 4; r++) {
            const int b = blockM + waveM * 64 + mi * 16 + quad * 4 + r;
            float p = 0.0f;
#pragma unroll
            for (int ni = 0; ni < 4; ni++) {
                const int j = blockN + waveN * 64 + ni * 16 + l16;
                p += acc[mi][ni][r] * Xf[(size_t)b * F + j];
            }
            p += __shfl_xor(p, 1);
            p += __shfl_xor(p, 2);
            p += __shfl_xor(p, 4);
            p += __shfl_xor(p, 8);
            if (l16 == 0) atomicAdd(&rowacc[b], p);
        }
    }
}

__global__ void sigmoid_kernel(const float* __restrict__ acc, float* __restrict__ out) {
    int b = blockIdx.x * blockDim.x + threadIdx.x;
    out[b] = 1.0f / (1.0f + __expf(-acc[b]));
}

// Correctness fallback if workspace is too small: direct per-row computation.
__global__ void fallback_kernel(const float* __restrict__ x, const float* __restrict__ w,
                                float* __restrict__ out) {
    __shared__ float xs[F];
    __shared__ float partial[4];
    const int b = blockIdx.x;
    for (int i = threadIdx.x; i < F; i += 256) xs[i] = x[(size_t)b * F + i];
    __syncthreads();
    float s = 0.0f;
    for (int i = threadIdx.x; i < F - 1; i += 256) {
        const float xi = xs[i];
        const int kbase = i * (F - 1) - (i * (i - 1)) / 2 - i - 1;
        for (int j = i + 1; j < F; j++) s += w[kbase + j] * xi * xs[j];
    }
    for (int off = 32; off; off >>= 1) s += __shfl_down(s, off);
    if ((threadIdx.x & 63) == 0) partial[threadIdx.x >> 6] = s;
    __syncthreads();
    if (threadIdx.x == 0) {
        float t = partial[0] + partial[1] + partial[2] + partial[3];
        out[b] = 1.0f / (1.0f + __expf(-t));
    }
}

extern "C" void kernel_launch(void* const* d_in, const int* in_sizes, int n_in,
                              void* d_out, int out_size, void* d_ws, size_t ws_size,
                              hipStream_t stream) {
    const float* x = (const float*)d_in[0];
    const float* w = (const float*)d_in[1];
    float* out = (float*)d_out;

    const size_t acc_bytes = 65536;                       // 16384 fp32 (rounded)
    const size_t A_bytes   = (size_t)F * F * 2;           // 2 MiB bf16
    const size_t Xb_bytes  = (size_t)B_ROWS * F * 2;      // 32 MiB bf16
    const size_t needed = acc_bytes + A_bytes + Xb_bytes;

    if (ws_size < needed) {
        fallback_kernel<<<B_ROWS, 256, 0, stream>>>(x, w, out);
        return;
    }

    float*    acc = (float*)d_ws;
    ushort_t* A   = (ushort_t*)((char*)d_ws + acc_bytes);
    ushort_t* Xb  = (ushort_t*)((char*)d_ws + acc_bytes + A_bytes);

    // prep: 64 (acc zero) + 4096 (build A) + 8192 (convert X) blocks
    prep_kernel<<<64 + 4096 + 8192, 256, 0, stream>>>(w, x, A, Xb, acc);
    dim3 grid(F / 128, B_ROWS / 128, SPLITK);
    gemm_kernel<<<grid, 256, 0, stream>>>(Xb, A, x, acc);
    sigmoid_kernel<<<B_ROWS / 256, 256, 0, stream>>>(acc, out);
}